// Round 15
// baseline (209.500 us; speedup 1.0000x reference)
//
#include <hip/hip_runtime.h>
#include <hip/hip_bf16.h>

typedef _Float16 half_t;
typedef _Float16 f16x8 __attribute__((ext_vector_type(8)));
typedef float f32x4 __attribute__((ext_vector_type(4)));

#define AS1 __attribute__((address_space(1)))
#define AS3 __attribute__((address_space(3)))

constexpr int CB = 512;    // channels
constexpr int NB = 2048;   // sequence length
constexpr int BB = 8;      // batch

__device__ inline f32x4 mfma16(f16x8 a, f16x8 b, f32x4 c) {
  return __builtin_amdgcn_mfma_f32_16x16x32_f16(a, b, c, 0, 0, 0);
}

// T1: XCD-aware bijective block remap (requires nwg % 8 == 0; else identity)
__device__ inline void xcd_swizzle(int& bx, int& by, int& bz) {
  const int gx = gridDim.x, gy = gridDim.y, gz = gridDim.z;
  const int nwg = gx * gy * gz;
  int lin = blockIdx.x + gx * (blockIdx.y + gy * blockIdx.z);
  if ((nwg & 7) == 0) {
    const int q = nwg >> 3;
    lin = (lin & 7) * q + (lin >> 3);
  }
  bx = lin % gx;
  int tmp = lin / gx;
  by = tmp % gy;
  bz = tmp / gy;
}

// ---------------- merged: wv -> fp16 (blocks 0..1023) + u[d] = sum_o bq[o]*wk[o][d] (block 1024)
__global__ void prep_wu(const float* __restrict__ wv, const float* __restrict__ wk,
                        const float* __restrict__ bq,
                        half_t* __restrict__ wvh, float* __restrict__ u) {
  if (blockIdx.x < 1024) {
    int i = blockIdx.x * 256 + threadIdx.x;
    if (i < CB * CB) wvh[i] = (half_t)wv[i];
  } else {
    int d = (blockIdx.x - 1024) * 256 + threadIdx.x;
    if (d < CB) {
      float s = 0.0f;
      for (int o = 0; o < CB; o++) s += bq[o] * wk[(size_t)o * CB + d];
      u[d] = s;
    }
  }
}

// ---------------- G partials: Gp[z][c][d] = sum_{o in chunk z} wq[o][c]*wk[o][d]
__global__ __launch_bounds__(256) void compute_G_part(const float* __restrict__ wq,
                                                      const float* __restrict__ wk,
                                                      float* __restrict__ Gp) {
  __shared__ float aq[64][68];
  __shared__ float ak[64][68];
  const int c0 = blockIdx.y * 64, d0 = blockIdx.x * 64, o0 = blockIdx.z * 64;
  const int t = threadIdx.x;
  {
    const int r = t >> 2, cbase = (t & 3) * 16;
    const float* q = wq + (size_t)(o0 + r) * CB + c0 + cbase;
    const float* k = wk + (size_t)(o0 + r) * CB + d0 + cbase;
#pragma unroll
    for (int q4 = 0; q4 < 4; q4++) {
      *(float4*)&aq[r][cbase + q4 * 4] = *(const float4*)(q + q4 * 4);
      *(float4*)&ak[r][cbase + q4 * 4] = *(const float4*)(k + q4 * 4);
    }
  }
  __syncthreads();
  const int tc = t & 15, td = t >> 4;
  float acc[4][4] = {};
#pragma unroll 8
  for (int o = 0; o < 64; o++) {
    float4 a4 = *(const float4*)&aq[o][tc * 4];
    float4 b4 = *(const float4*)&ak[o][td * 4];
    float av[4] = {a4.x, a4.y, a4.z, a4.w};
    float bv[4] = {b4.x, b4.y, b4.z, b4.w};
#pragma unroll
    for (int i = 0; i < 4; i++)
#pragma unroll
      for (int j = 0; j < 4; j++)
        acc[i][j] += av[i] * bv[j];
  }
  float* gz = Gp + (size_t)blockIdx.z * CB * CB;
#pragma unroll
  for (int i = 0; i < 4; i++) {
    int c = c0 + tc * 4 + i;
#pragma unroll
    for (int j = 0; j < 4; j++)
      gz[(size_t)c * CB + d0 + td * 4 + j] = acc[i][j];
  }
}

// ---------------- reduce 8 partials -> G fp16
__global__ void reduce_G(const float* __restrict__ Gp, half_t* __restrict__ Gh) {
  int i = blockIdx.x * 256 + threadIdx.x;
  if (i >= CB * CB) return;
  float s = 0.0f;
#pragma unroll
  for (int z = 0; z < 8; z++) s += Gp[(size_t)z * CB * CB + i];
  Gh[i] = (half_t)s;
}

// ---------------- ubias[row] = sum_c u[c] * xh[row][c], row in [0, B*N)
__global__ __launch_bounds__(256) void compute_ubias(const half_t* __restrict__ xh,
                                                     const float* __restrict__ u,
                                                     float* __restrict__ ub) {
  __shared__ float us[CB];
  for (int i = threadIdx.x; i < CB; i += 256) us[i] = u[i];
  __syncthreads();
  int row = blockIdx.x * 4 + (threadIdx.x >> 6);
  int lane = threadIdx.x & 63;
  f16x8 vh = *(const f16x8*)(xh + (size_t)row * CB + lane * 8);
  float s = 0.0f;
#pragma unroll
  for (int i = 0; i < 8; i++) s += us[lane * 8 + i] * (float)vh[i];
#pragma unroll
  for (int off = 32; off; off >>= 1) s += __shfl_xor(s, off);
  if (lane == 0) ub[row] = s;
}

// ---------------- x [B][C][N] fp32 -> xh [B][N][C] fp16 (transpose) + xn [B][C][N] fp16
__global__ void transpose_x(const float* __restrict__ x, half_t* __restrict__ oh,
                            half_t* __restrict__ xn) {
  __shared__ float tile[32][33];
  int b = blockIdx.z, c0 = blockIdx.y * 32, n0 = blockIdx.x * 32;
  int tx = threadIdx.x, ty = threadIdx.y;          // block (32, 8)
  const float* xb = x + (size_t)b * CB * NB;
  half_t* xnb = xn + (size_t)b * CB * NB;
#pragma unroll
  for (int r = 0; r < 4; r++) {
    float v = xb[(size_t)(c0 + ty + 8 * r) * NB + n0 + tx];
    tile[ty + 8 * r][tx] = v;
    xnb[(size_t)(c0 + ty + 8 * r) * NB + n0 + tx] = (half_t)v;
  }
  __syncthreads();
  size_t base = (size_t)b * NB * CB;
#pragma unroll
  for (int r = 0; r < 4; r++)
    oh[base + (size_t)(n0 + ty + 8 * r) * CB + c0 + tx] = (half_t)tile[tx][ty + 8 * r];
}

// ---------------- GEMM-NT 128^2, 3-buffer counted-vmcnt pipeline (T4), fp16, T1 swizzle
// Race-free by construction:
//  - stage(kt+2) -> buf[(kt+2)%3], last read in iter kt-1; all waves passed the end-of-(kt-1)
//    barrier (their ds_reads completed before their MFMAs) before any wave issues it.
//  - ds_read buf[kt%3]: staged at iter kt-2; vmcnt(4) at end of kt-1 leaves only kt+1's 4 loads
//    outstanding => kt's loads landed, published by the barrier.
//  - vmcnt drains to 0 only once (last tile's loads).
// BIAS: 0 none, 1 batched col-bias. EPI: 3 f32 + fp16 residual R; 4 int16 fixed-point
template <int BIAS, int EPI, int NT>
__global__ __launch_bounds__(256) void gemm_nt(
    const half_t* __restrict__ A, int lda, long sA,
    const half_t* __restrict__ Bh, int ldb, long sB,
    void* __restrict__ D, int ldd, long sD,
    const float* __restrict__ bias, long sBias,
    const half_t* __restrict__ R, int ldr, long sR) {
  constexpr int TSZ = 128 * 32;
  __shared__ alignas(16) half_t sm[3 * 2 * TSZ];   // 3 bufs x (A 8KB + B 8KB) = 48 KB

  int bxi, byi, bzi;
  xcd_swizzle(bxi, byi, bzi);
  const int t = threadIdx.x;
  const int z = bzi;
  const half_t* Ab  = A  + (size_t)z * sA + (size_t)(byi * 128) * lda;
  const half_t* Bbh = Bh + (size_t)z * sB + (size_t)(bxi * 128) * ldb;
  const int wid = t >> 6, l15 = t & 15, hi = (t >> 4) & 3;
  const int wr = wid >> 1, wc = wid & 1;
  const int lineA = t >> 2, eoff = (t & 3) * 8;

  f32x4 acc[4][4] = {};

  auto stage = [&](int buf, int kt) {   // 4 global_load_lds per thread
    half_t* base = sm + buf * (2 * TSZ);
#pragma unroll
    for (int p = 0; p < 2; p++) {
      size_t goA = (size_t)(p * 64 + lineA) * lda + kt * 32 + eoff;
      size_t goB = (size_t)(p * 64 + lineA) * ldb + kt * 32 + eoff;
      int lo = p * 2048 + t * 8;
      __builtin_amdgcn_global_load_lds((const AS1 void*)(Ab + goA),  (AS3 void*)(base + lo), 16, 0, 0);
      __builtin_amdgcn_global_load_lds((const AS1 void*)(Bbh + goB), (AS3 void*)(base + TSZ + lo), 16, 0, 0);
    }
  };

  // prologue: kt0 -> buf0, kt1 -> buf1; wait until kt0 landed (kt1 stays in flight)
  stage(0, 0);
  stage(1, 1);
  asm volatile("s_waitcnt vmcnt(4)" ::: "memory");
  __builtin_amdgcn_s_barrier();
  asm volatile("" ::: "memory");

  int rb = 0;                            // buffer holding K-tile kt
  for (int kt = 0; kt < NT; kt++) {
    if (kt + 2 < NT) {
      int sb = rb + 2; if (sb >= 3) sb -= 3;
      stage(sb, kt + 2);
    }
    const half_t* bb = sm + rb * (2 * TSZ);
    f16x8 af[4], bf[4];
#pragma unroll
    for (int f = 0; f < 4; f++) {
      af[f] = *(const f16x8*)(bb + (wr * 64 + f * 16 + l15) * 32 + hi * 8);
      bf[f] = *(const f16x8*)(bb + TSZ + (wc * 64 + f * 16 + l15) * 32 + hi * 8);
    }
#pragma unroll
    for (int fm = 0; fm < 4; fm++)
#pragma unroll
      for (int fn = 0; fn < 4; fn++)
        acc[fm][fn] = mfma16(af[fm], bf[fn], acc[fm][fn]);

    if (kt + 1 < NT) {
      if (kt + 2 < NT) asm volatile("s_waitcnt vmcnt(4)" ::: "memory");
      else             asm volatile("s_waitcnt vmcnt(0)" ::: "memory");
      __builtin_amdgcn_s_barrier();
      asm volatile("" ::: "memory");
    }
    rb = (rb + 1 == 3) ? 0 : rb + 1;
  }

  const int row0 = byi * 128 + wr * 64;
  const int col0 = bxi * 128 + wc * 64;
#pragma unroll
  for (int fm = 0; fm < 4; fm++) {
    int rowb = row0 + fm * 16 + hi * 4;
#pragma unroll
    for (int fn = 0; fn < 4; fn++) {
      int col = col0 + fn * 16 + l15;
      float bc = (BIAS == 1) ? bias[(size_t)z * sBias + col] : 0.0f;
#pragma unroll
      for (int r = 0; r < 4; r++) {
        float val = acc[fm][fn][r] + bc;
        size_t di = (size_t)(rowb + r) * ldd + col;
        if (EPI == 3) {
          val += (float)R[(size_t)z * sR + (size_t)(rowb + r) * ldr + col];
          ((float*)D)[(size_t)z * sD + di] = val;
        } else {  // EPI == 4: int16 fixed-point, scale 256
          float sv = fminf(fmaxf(val * 256.0f, -32767.0f), 32767.0f);
          ((short*)D)[(size_t)z * sD + di] = (short)__float2int_rn(sv);
        }
      }
    }
  }
}

// ---------------- merged YT + V GEMM (one dispatch, grid (16,4,16)) — unchanged control
__global__ __launch_bounds__(256) void gemm_vyt(
    const half_t* __restrict__ xh, const half_t* __restrict__ wvh,
    const half_t* __restrict__ Gh, const float* __restrict__ bv,
    half_t* __restrict__ v, half_t* __restrict__ YTh) {
  constexpr int TSZ = 128 * 32;
  __shared__ alignas(16) half_t sm[2 * 2 * TSZ];

  int bxi, byi, bzi;
  xcd_swizzle(bxi, byi, bzi);
  const int t = threadIdx.x;

  const half_t* Ab;
  const half_t* Bb;
  half_t* Dz;
  int ldd, row0b, col0b;
  const float* rowbias = nullptr;
  if (bzi < 8) {           // V-mode
    const int z = bzi;
    Ab = wvh + (size_t)(byi * 128) * CB;
    Bb = xh + (size_t)z * NB * CB + (size_t)(bxi * 128) * CB;
    Dz = v + (size_t)z * CB * NB;
    ldd = NB; row0b = byi * 128; col0b = bxi * 128;
    rowbias = bv;
  } else {                 // YT-mode
    const int z = bzi - 8;
    const int lin2 = byi * 16 + bxi;        // [0,64)
    const int xp = lin2 & 3, yp = lin2 >> 2;
    Ab = xh + (size_t)z * NB * CB + (size_t)(yp * 128) * CB;
    Bb = Gh + (size_t)(xp * 128) * CB;
    Dz = YTh + (size_t)z * NB * CB;
    ldd = CB; row0b = yp * 128; col0b = xp * 128;
  }

  const int wid = t >> 6, l15 = t & 15, hi = (t >> 4) & 3;
  const int wr = wid >> 1, wc = wid & 1;
  const int lineA = t >> 2, eoff = (t & 3) * 8;

  f32x4 acc[4][4] = {};

  auto stage = [&](int buf, int kt) {
    half_t* base = sm + buf * (2 * TSZ);
#pragma unroll
    for (int p = 0; p < 2; p++) {
      size_t go = (size_t)(p * 64 + lineA) * CB + kt * 32 + eoff;
      int lo = p * 2048 + t * 8;
      __builtin_amdgcn_global_load_lds((const AS1 void*)(Ab + go), (AS3 void*)(base + lo), 16, 0, 0);
      __builtin_amdgcn_global_load_lds((const AS1 void*)(Bb + go), (AS3 void*)(base + TSZ + lo), 16, 0, 0);
    }
  };

  stage(0, 0);
  __syncthreads();
  int cur = 0;
  for (int kt = 0; kt < 16; kt++) {
    if (kt + 1 < 16) stage(cur ^ 1, kt + 1);
    const half_t* bb = sm + cur * (2 * TSZ);
    f16x8 af[4], bf[4];
#pragma unroll
    for (int f = 0; f < 4; f++) {
      af[f] = *(const f16x8*)(bb + (wr * 64 + f * 16 + l15) * 32 + hi * 8);
      bf[f] = *(const f16x8*)(bb + TSZ + (wc * 64 + f * 16 + l15) * 32 + hi * 8);
    }
#pragma unroll
    for (int fm = 0; fm < 4; fm++)
#pragma unroll
      for (int fn = 0; fn < 4; fn++)
        acc[fm][fn] = mfma16(af[fm], bf[fn], acc[fm][fn]);
    __syncthreads();
    cur ^= 1;
  }

  const int row0 = row0b + wr * 64;
  const int col0 = col0b + wc * 64;
#pragma unroll
  for (int fm = 0; fm < 4; fm++) {
    int rowb = row0 + fm * 16 + hi * 4;
#pragma unroll
    for (int fn = 0; fn < 4; fn++) {
      int col = col0 + fn * 16 + l15;
#pragma unroll
      for (int r = 0; r < 4; r++) {
        float val = acc[fm][fn][r];
        if (rowbias) val += rowbias[rowb + r];
        Dz[(size_t)(rowb + r) * ldd + col] = (half_t)val;
      }
    }
  }
}

// ---------------- row softmax over S int16 [rows][2048] (scale 1/256); writes dense P fp16
struct alignas(16) H8 { half_t h[8]; };
struct alignas(16) S8 { short s[8]; };

__global__ __launch_bounds__(256) void softmax_rows(const short* __restrict__ S,
                                                    half_t* __restrict__ P) {
  const short* row = S + (size_t)blockIdx.x * NB;
  int t = threadIdx.x;
  S8 r8 = *reinterpret_cast<const S8*>(row + t * 8);
  float vals[8];
#pragma unroll
  for (int i = 0; i < 8; i++) vals[i] = (float)r8.s[i] * 0.00390625f;
  float m = vals[0];
#pragma unroll
  for (int i = 1; i < 8; i++) m = fmaxf(m, vals[i]);
#pragma unroll
  for (int off = 32; off; off >>= 1) m = fmaxf(m, __shfl_xor(m, off));
  __shared__ float redm[4], reds[4];
  if ((t & 63) == 0) redm[t >> 6] = m;
  __syncthreads();
  m = fmaxf(fmaxf(redm[0], redm[1]), fmaxf(redm[2], redm[3]));
  float e[8], s = 0.0f;
#pragma unroll
  for (int i = 0; i < 8; i++) { e[i] = __expf(vals[i] - m); s += e[i]; }
#pragma unroll
  for (int off = 32; off; off >>= 1) s += __shfl_xor(s, off);
  if ((t & 63) == 0) reds[t >> 6] = s;
  __syncthreads();
  s = reds[0] + reds[1] + reds[2] + reds[3];
  float inv = 1.0f / s;
  H8 ob;
#pragma unroll
  for (int i = 0; i < 8; i++) ob.h[i] = (half_t)(e[i] * inv);
  *reinterpret_cast<H8*>(P + (size_t)blockIdx.x * NB + t * 8) = ob;
}

// ---------------- launcher
extern "C" void kernel_launch(void* const* d_in, const int* in_sizes, int n_in,
                              void* d_out, int out_size, void* d_ws, size_t ws_size,
                              hipStream_t stream) {
  const float* x  = (const float*)d_in[0];
  const float* wq = (const float*)d_in[1];
  const float* bq = (const float*)d_in[2];
  const float* wk = (const float*)d_in[3];
  const float* wv = (const float*)d_in[5];
  const float* bv = (const float*)d_in[6];
  float* out = (float*)d_out;

  const size_t MB = 1u << 20;
  if (ws_size < 196 * MB) return;

  char* ws = (char*)d_ws;
  half_t* xh   = (half_t*)(ws + 0);            // [B][N][C]    16 MB
  half_t* YTh  = (half_t*)(ws + 16 * MB);      // [B][N][C]    16 MB
  half_t* v    = (half_t*)(ws + 32 * MB);      // [B][C][N]    16 MB
  short*  Ss   = (short*)(ws + 48 * MB);       // [8][N][N]    64 MB (int16 logits, scale 256)
  float*  Gp   = (float*)(ws + 48 * MB);       // [8][C][C]     8 MB (overlay; dead before S)
  half_t* Pd   = (half_t*)(ws + 112 * MB);     // [8][N][N]    64 MB (dense P)
  half_t* xn   = (half_t*)(ws + 176 * MB);     // [B][C][N]    16 MB (fp16 residual copy)
  half_t* Gh   = (half_t*)(ws + 192 * MB);     // [C][C]      0.5 MB
  half_t* wvh  = (half_t*)(ws + 192 * MB + 512 * 1024);  // [C][C]  0.5 MB
  float*  u    = (float*)(ws + 193 * MB);                // [C]       2 KB
  float*  ub   = (float*)(ws + 193 * MB + 256 * 1024);   // [B][N]   64 KB

  prep_wu<<<1026, 256, 0, stream>>>(wv, wk, bq, wvh, u);
  compute_G_part<<<dim3(8, 8, 8), 256, 0, stream>>>(wq, wk, Gp);
  reduce_G<<<1024, 256, 0, stream>>>(Gp, Gh);
  transpose_x<<<dim3(64, 16, 8), dim3(32, 8), 0, stream>>>(x, xh, xn);
  compute_ubias<<<BB * NB / 4, 256, 0, stream>>>(xh, u, ub);

  // merged: v = wvh*xh^T + bv  (z<8)  and  YT = xh*Gh^T  (z>=8)
  gemm_vyt<<<dim3(16, 4, 16), 256, 0, stream>>>(xh, wvh, Gh, bv, v, YTh);

  // S[z][i][j] = sum_c xh[i][c]*YTh[j][c] + ub[z][j]  -> int16 (scale 256)
  gemm_nt<1, 4, 16><<<dim3(16, 16, 8), 256, 0, stream>>>(
      xh, CB, (long)NB * CB,
      YTh, CB, (long)NB * CB,
      Ss, NB, (long)NB * NB, ub, NB, nullptr, 0, 0);

  softmax_rows<<<BB * NB, 256, 0, stream>>>(Ss, Pd);

  // out[z][ch][i] = sum_j v[z][ch][j]*Pd[z][i][j] + xn[z][ch][i]
  gemm_nt<0, 3, 64><<<dim3(16, 4, 8), 256, 0, stream>>>(
      v, NB, (long)CB * NB,
      Pd, NB, (long)NB * NB,
      out, NB, (long)CB * NB, nullptr, 0,
      xn, NB, (long)CB * NB);
}

// Round 16
// 201.759 us; speedup vs baseline: 1.0384x; 1.0384x over previous
//
#include <hip/hip_runtime.h>
#include <hip/hip_bf16.h>

typedef _Float16 half_t;
typedef _Float16 f16x8 __attribute__((ext_vector_type(8)));
typedef float f32x4 __attribute__((ext_vector_type(4)));

#define AS1 __attribute__((address_space(1)))
#define AS3 __attribute__((address_space(3)))

constexpr int CB = 512;    // channels
constexpr int NB = 2048;   // sequence length
constexpr int BB = 8;      // batch

__device__ inline f32x4 mfma16(f16x8 a, f16x8 b, f32x4 c) {
  return __builtin_amdgcn_mfma_f32_16x16x32_f16(a, b, c, 0, 0, 0);
}

// T1: XCD-aware bijective block remap (requires nwg % 8 == 0; else identity)
__device__ inline void xcd_swizzle(int& bx, int& by, int& bz) {
  const int gx = gridDim.x, gy = gridDim.y, gz = gridDim.z;
  const int nwg = gx * gy * gz;
  int lin = blockIdx.x + gx * (blockIdx.y + gy * blockIdx.z);
  if ((nwg & 7) == 0) {
    const int q = nwg >> 3;
    lin = (lin & 7) * q + (lin >> 3);
  }
  bx = lin % gx;
  int tmp = lin / gx;
  by = tmp % gy;
  bz = tmp / gy;
}

// ================ merged preprocessing stage 1 ================
// blocks [0, 8192): transpose_x  — x [B][C][N] f32 -> xh [B][N][C] fp16 + xn [B][C][N] fp16
// blocks [8192, 8704): compute_G_part — Gp[z][c][d] partials
// blocks [8704, 9730): prep_wu — wv->fp16 and u[d]
__global__ __launch_bounds__(256) void prep_all(
    const float* __restrict__ x, const float* __restrict__ wq,
    const float* __restrict__ wk, const float* __restrict__ wv,
    const float* __restrict__ bq,
    half_t* __restrict__ xh, half_t* __restrict__ xn,
    half_t* __restrict__ wvh, float* __restrict__ u, float* __restrict__ Gp) {
  __shared__ float smem[64 * 68 * 2];   // 34.8 KB, aliased per branch
  const int b = blockIdx.x;
  const int t = threadIdx.x;

  if (b < 8192) {
    // ---- transpose_x: b -> (bx 64, by 16, bz 8)
    float (*tile)[33] = (float(*)[33])smem;
    const int bz = b >> 10, by = (b >> 6) & 15, bx = b & 63;
    const int c0 = by * 32, n0 = bx * 32;
    const int tx = t & 31, ty = t >> 5;
    const float* xb = x + (size_t)bz * CB * NB;
    half_t* xnb = xn + (size_t)bz * CB * NB;
#pragma unroll
    for (int r = 0; r < 4; r++) {
      float v = xb[(size_t)(c0 + ty + 8 * r) * NB + n0 + tx];
      tile[ty + 8 * r][tx] = v;
      xnb[(size_t)(c0 + ty + 8 * r) * NB + n0 + tx] = (half_t)v;
    }
    __syncthreads();
    size_t base = (size_t)bz * NB * CB;
#pragma unroll
    for (int r = 0; r < 4; r++)
      xh[base + (size_t)(n0 + ty + 8 * r) * CB + c0 + tx] = (half_t)tile[tx][ty + 8 * r];
  } else if (b < 8704) {
    // ---- compute_G_part: g -> (dx 8, cy 8, oz 8)
    const int g = b - 8192;
    const int d0 = (g & 7) * 64, c0 = ((g >> 3) & 7) * 64, o0 = (g >> 6) * 64;
    float (*aq)[68] = (float(*)[68])smem;
    float (*ak)[68] = (float(*)[68])(smem + 64 * 68);
    {
      const int r = t >> 2, cbase = (t & 3) * 16;
      const float* q = wq + (size_t)(o0 + r) * CB + c0 + cbase;
      const float* k = wk + (size_t)(o0 + r) * CB + d0 + cbase;
#pragma unroll
      for (int q4 = 0; q4 < 4; q4++) {
        *(float4*)&aq[r][cbase + q4 * 4] = *(const float4*)(q + q4 * 4);
        *(float4*)&ak[r][cbase + q4 * 4] = *(const float4*)(k + q4 * 4);
      }
    }
    __syncthreads();
    const int tc = t & 15, td = t >> 4;
    float acc[4][4] = {};
#pragma unroll 8
    for (int o = 0; o < 64; o++) {
      float4 a4 = *(const float4*)&aq[o][tc * 4];
      float4 b4 = *(const float4*)&ak[o][td * 4];
      float av[4] = {a4.x, a4.y, a4.z, a4.w};
      float bv[4] = {b4.x, b4.y, b4.z, b4.w};
#pragma unroll
      for (int i = 0; i < 4; i++)
#pragma unroll
        for (int j = 0; j < 4; j++)
          acc[i][j] += av[i] * bv[j];
    }
    float* gz = Gp + (size_t)(g >> 6) * CB * CB;
#pragma unroll
    for (int i = 0; i < 4; i++) {
      int c = c0 + tc * 4 + i;
#pragma unroll
      for (int j = 0; j < 4; j++)
        gz[(size_t)c * CB + d0 + td * 4 + j] = acc[i][j];
    }
  } else {
    // ---- prep_wu
    const int p = b - 8704;
    if (p < 1024) {
      int i = p * 256 + t;
      if (i < CB * CB) wvh[i] = (half_t)wv[i];
    } else {
      int d = (p - 1024) * 256 + t;
      if (d < CB) {
        float s = 0.0f;
        for (int o = 0; o < CB; o++) s += bq[o] * wk[(size_t)o * CB + d];
        u[d] = s;
      }
    }
  }
}

// ================ merged preprocessing stage 2 ================
// blocks [0,1024): reduce_G ; blocks [1024, 5120): compute_ubias
__global__ __launch_bounds__(256) void prep2(
    const float* __restrict__ Gp, half_t* __restrict__ Gh,
    const half_t* __restrict__ xh, const float* __restrict__ u,
    float* __restrict__ ub) {
  const int b = blockIdx.x;
  const int t = threadIdx.x;
  if (b < 1024) {
    int i = b * 256 + t;
    if (i < CB * CB) {
      float s = 0.0f;
#pragma unroll
      for (int z = 0; z < 8; z++) s += Gp[(size_t)z * CB * CB + i];
      Gh[i] = (half_t)s;
    }
  } else {
    __shared__ float us[CB];
    for (int i = t; i < CB; i += 256) us[i] = u[i];
    __syncthreads();
    int row = (b - 1024) * 4 + (t >> 6);
    int lane = t & 63;
    f16x8 vh = *(const f16x8*)(xh + (size_t)row * CB + lane * 8);
    float s = 0.0f;
#pragma unroll
    for (int i = 0; i < 8; i++) s += us[lane * 8 + i] * (float)vh[i];
#pragma unroll
    for (int off = 32; off; off >>= 1) s += __shfl_xor(s, off);
    if (lane == 0) ub[row] = s;
  }
}

// ---------------- GEMM-NT (proven 128^2 2-barrier, fp16) + T1 swizzle
// BIAS: 0 none, 1 batched col-bias. EPI: 3 f32 + fp16 residual R; 4 int16 fixed-point
template <int BIAS, int EPI, int NT>
__global__ __launch_bounds__(256) void gemm_nt(
    const half_t* __restrict__ A, int lda, long sA,
    const half_t* __restrict__ Bh, int ldb, long sB,
    void* __restrict__ D, int ldd, long sD,
    const float* __restrict__ bias, long sBias,
    const half_t* __restrict__ R, int ldr, long sR) {
  constexpr int TSZ = 128 * 32;
  __shared__ alignas(16) half_t sm[2 * 2 * TSZ];

  int bxi, byi, bzi;
  xcd_swizzle(bxi, byi, bzi);
  const int t = threadIdx.x;
  const int z = bzi;
  const half_t* Ab  = A  + (size_t)z * sA + (size_t)(byi * 128) * lda;
  const half_t* Bbh = Bh + (size_t)z * sB + (size_t)(bxi * 128) * ldb;
  const int wid = t >> 6, l15 = t & 15, hi = (t >> 4) & 3;
  const int wr = wid >> 1, wc = wid & 1;
  const int lineA = t >> 2, eoff = (t & 3) * 8;

  f32x4 acc[4][4] = {};

  auto stage = [&](int buf, int kt) {
    half_t* base = sm + buf * (2 * TSZ);
#pragma unroll
    for (int p = 0; p < 2; p++) {
      size_t goA = (size_t)(p * 64 + lineA) * lda + kt * 32 + eoff;
      size_t goB = (size_t)(p * 64 + lineA) * ldb + kt * 32 + eoff;
      int lo = p * 2048 + t * 8;
      __builtin_amdgcn_global_load_lds((const AS1 void*)(Ab + goA),  (AS3 void*)(base + lo), 16, 0, 0);
      __builtin_amdgcn_global_load_lds((const AS1 void*)(Bbh + goB), (AS3 void*)(base + TSZ + lo), 16, 0, 0);
    }
  };

  stage(0, 0);
  __syncthreads();
  int cur = 0;
  for (int kt = 0; kt < NT; kt++) {
    if (kt + 1 < NT) stage(cur ^ 1, kt + 1);
    const half_t* bb = sm + cur * (2 * TSZ);
    f16x8 af[4], bf[4];
#pragma unroll
    for (int f = 0; f < 4; f++) {
      af[f] = *(const f16x8*)(bb + (wr * 64 + f * 16 + l15) * 32 + hi * 8);
      bf[f] = *(const f16x8*)(bb + TSZ + (wc * 64 + f * 16 + l15) * 32 + hi * 8);
    }
#pragma unroll
    for (int fm = 0; fm < 4; fm++)
#pragma unroll
      for (int fn = 0; fn < 4; fn++)
        acc[fm][fn] = mfma16(af[fm], bf[fn], acc[fm][fn]);
    __syncthreads();
    cur ^= 1;
  }

  const int row0 = byi * 128 + wr * 64;
  const int col0 = bxi * 128 + wc * 64;
#pragma unroll
  for (int fm = 0; fm < 4; fm++) {
    int rowb = row0 + fm * 16 + hi * 4;
#pragma unroll
    for (int fn = 0; fn < 4; fn++) {
      int col = col0 + fn * 16 + l15;
      float bc = (BIAS == 1) ? bias[(size_t)z * sBias + col] : 0.0f;
#pragma unroll
      for (int r = 0; r < 4; r++) {
        float val = acc[fm][fn][r] + bc;
        size_t di = (size_t)(rowb + r) * ldd + col;
        if (EPI == 3) {
          val += (float)R[(size_t)z * sR + (size_t)(rowb + r) * ldr + col];
          ((float*)D)[(size_t)z * sD + di] = val;
        } else {  // EPI == 4: int16 fixed-point, scale 256
          float sv = fminf(fmaxf(val * 256.0f, -32767.0f), 32767.0f);
          ((short*)D)[(size_t)z * sD + di] = (short)__float2int_rn(sv);
        }
      }
    }
  }
}

// ---------------- merged YT + V GEMM (one dispatch, grid (16,4,16))
__global__ __launch_bounds__(256) void gemm_vyt(
    const half_t* __restrict__ xh, const half_t* __restrict__ wvh,
    const half_t* __restrict__ Gh, const float* __restrict__ bv,
    half_t* __restrict__ v, half_t* __restrict__ YTh) {
  constexpr int TSZ = 128 * 32;
  __shared__ alignas(16) half_t sm[2 * 2 * TSZ];

  int bxi, byi, bzi;
  xcd_swizzle(bxi, byi, bzi);
  const int t = threadIdx.x;

  const half_t* Ab;
  const half_t* Bb;
  half_t* Dz;
  int ldd, row0b, col0b;
  const float* rowbias = nullptr;
  if (bzi < 8) {           // V-mode
    const int z = bzi;
    Ab = wvh + (size_t)(byi * 128) * CB;
    Bb = xh + (size_t)z * NB * CB + (size_t)(bxi * 128) * CB;
    Dz = v + (size_t)z * CB * NB;
    ldd = NB; row0b = byi * 128; col0b = bxi * 128;
    rowbias = bv;
  } else {                 // YT-mode
    const int z = bzi - 8;
    const int lin2 = byi * 16 + bxi;        // [0,64)
    const int xp = lin2 & 3, yp = lin2 >> 2;
    Ab = xh + (size_t)z * NB * CB + (size_t)(yp * 128) * CB;
    Bb = Gh + (size_t)(xp * 128) * CB;
    Dz = YTh + (size_t)z * NB * CB;
    ldd = CB; row0b = yp * 128; col0b = xp * 128;
  }

  const int wid = t >> 6, l15 = t & 15, hi = (t >> 4) & 3;
  const int wr = wid >> 1, wc = wid & 1;
  const int lineA = t >> 2, eoff = (t & 3) * 8;

  f32x4 acc[4][4] = {};

  auto stage = [&](int buf, int kt) {
    half_t* base = sm + buf * (2 * TSZ);
#pragma unroll
    for (int p = 0; p < 2; p++) {
      size_t go = (size_t)(p * 64 + lineA) * CB + kt * 32 + eoff;
      int lo = p * 2048 + t * 8;
      __builtin_amdgcn_global_load_lds((const AS1 void*)(Ab + go), (AS3 void*)(base + lo), 16, 0, 0);
      __builtin_amdgcn_global_load_lds((const AS1 void*)(Bb + go), (AS3 void*)(base + TSZ + lo), 16, 0, 0);
    }
  };

  stage(0, 0);
  __syncthreads();
  int cur = 0;
  for (int kt = 0; kt < 16; kt++) {
    if (kt + 1 < 16) stage(cur ^ 1, kt + 1);
    const half_t* bb = sm + cur * (2 * TSZ);
    f16x8 af[4], bf[4];
#pragma unroll
    for (int f = 0; f < 4; f++) {
      af[f] = *(const f16x8*)(bb + (wr * 64 + f * 16 + l15) * 32 + hi * 8);
      bf[f] = *(const f16x8*)(bb + TSZ + (wc * 64 + f * 16 + l15) * 32 + hi * 8);
    }
#pragma unroll
    for (int fm = 0; fm < 4; fm++)
#pragma unroll
      for (int fn = 0; fn < 4; fn++)
        acc[fm][fn] = mfma16(af[fm], bf[fn], acc[fm][fn]);
    __syncthreads();
    cur ^= 1;
  }

  const int row0 = row0b + wr * 64;
  const int col0 = col0b + wc * 64;
#pragma unroll
  for (int fm = 0; fm < 4; fm++) {
    int rowb = row0 + fm * 16 + hi * 4;
#pragma unroll
    for (int fn = 0; fn < 4; fn++) {
      int col = col0 + fn * 16 + l15;
#pragma unroll
      for (int r = 0; r < 4; r++) {
        float val = acc[fm][fn][r];
        if (rowbias) val += rowbias[rowb + r];
        Dz[(size_t)(rowb + r) * ldd + col] = (half_t)val;
      }
    }
  }
}

// ---------------- row softmax over S int16 [rows][2048] (scale 1/256); writes dense P fp16
struct alignas(16) H8 { half_t h[8]; };
struct alignas(16) S8 { short s[8]; };

__global__ __launch_bounds__(256) void softmax_rows(const short* __restrict__ S,
                                                    half_t* __restrict__ P) {
  const short* row = S + (size_t)blockIdx.x * NB;
  int t = threadIdx.x;
  S8 r8 = *reinterpret_cast<const S8*>(row + t * 8);
  float vals[8];
#pragma unroll
  for (int i = 0; i < 8; i++) vals[i] = (float)r8.s[i] * 0.00390625f;
  float m = vals[0];
#pragma unroll
  for (int i = 1; i < 8; i++) m = fmaxf(m, vals[i]);
#pragma unroll
  for (int off = 32; off; off >>= 1) m = fmaxf(m, __shfl_xor(m, off));
  __shared__ float redm[4], reds[4];
  if ((t & 63) == 0) redm[t >> 6] = m;
  __syncthreads();
  m = fmaxf(fmaxf(redm[0], redm[1]), fmaxf(redm[2], redm[3]));
  float e[8], s = 0.0f;
#pragma unroll
  for (int i = 0; i < 8; i++) { e[i] = __expf(vals[i] - m); s += e[i]; }
#pragma unroll
  for (int off = 32; off; off >>= 1) s += __shfl_xor(s, off);
  if ((t & 63) == 0) reds[t >> 6] = s;
  __syncthreads();
  s = reds[0] + reds[1] + reds[2] + reds[3];
  float inv = 1.0f / s;
  H8 ob;
#pragma unroll
  for (int i = 0; i < 8; i++) ob.h[i] = (half_t)(e[i] * inv);
  *reinterpret_cast<H8*>(P + (size_t)blockIdx.x * NB + t * 8) = ob;
}

// ---------------- launcher
extern "C" void kernel_launch(void* const* d_in, const int* in_sizes, int n_in,
                              void* d_out, int out_size, void* d_ws, size_t ws_size,
                              hipStream_t stream) {
  const float* x  = (const float*)d_in[0];
  const float* wq = (const float*)d_in[1];
  const float* bq = (const float*)d_in[2];
  const float* wk = (const float*)d_in[3];
  const float* wv = (const float*)d_in[5];
  const float* bv = (const float*)d_in[6];
  float* out = (float*)d_out;

  const size_t MB = 1u << 20;
  if (ws_size < 196 * MB) return;

  char* ws = (char*)d_ws;
  half_t* xh   = (half_t*)(ws + 0);            // [B][N][C]    16 MB
  half_t* YTh  = (half_t*)(ws + 16 * MB);      // [B][N][C]    16 MB
  half_t* v    = (half_t*)(ws + 32 * MB);      // [B][C][N]    16 MB
  short*  Ss   = (short*)(ws + 48 * MB);       // [8][N][N]    64 MB (int16 logits, scale 256)
  float*  Gp   = (float*)(ws + 48 * MB);       // [8][C][C]     8 MB (overlay; dead before S)
  half_t* Pd   = (half_t*)(ws + 112 * MB);     // [8][N][N]    64 MB (dense P)
  half_t* xn   = (half_t*)(ws + 176 * MB);     // [B][C][N]    16 MB (fp16 residual copy)
  half_t* Gh   = (half_t*)(ws + 192 * MB);     // [C][C]      0.5 MB
  half_t* wvh  = (half_t*)(ws + 192 * MB + 512 * 1024);  // [C][C]  0.5 MB
  float*  u    = (float*)(ws + 193 * MB);                // [C]       2 KB
  float*  ub   = (float*)(ws + 193 * MB + 256 * 1024);   // [B][N]   64 KB

  // stage 1: transpose + G partials + wv/u  (independent work, one dispatch)
  prep_all<<<9730, 256, 0, stream>>>(x, wq, wk, wv, bq, xh, xn, wvh, u, Gp);

  // stage 2: reduce G + ubias
  prep2<<<5120, 256, 0, stream>>>(Gp, Gh, xh, u, ub);

  // merged: v = wvh*xh^T + bv  (z<8)  and  YT = xh*Gh^T  (z>=8)
  gemm_vyt<<<dim3(16, 4, 16), 256, 0, stream>>>(xh, wvh, Gh, bv, v, YTh);

  // S[z][i][j] = sum_c xh[i][c]*YTh[j][c] + ub[z][j]  -> int16 (scale 256)
  gemm_nt<1, 4, 16><<<dim3(16, 16, 8), 256, 0, stream>>>(
      xh, CB, (long)NB * CB,
      YTh, CB, (long)NB * CB,
      Ss, NB, (long)NB * NB, ub, NB, nullptr, 0, 0);

  softmax_rows<<<BB * NB, 256, 0, stream>>>(Ss, Pd);

  // out[z][ch][i] = sum_j v[z][ch][j]*Pd[z][i][j] + xn[z][ch][i]
  gemm_nt<0, 3, 64><<<dim3(16, 4, 8), 256, 0, stream>>>(
      v, NB, (long)CB * NB,
      Pd, NB, (long)NB * NB,
      out, NB, (long)CB * NB, nullptr, 0,
      xn, NB, (long)CB * NB);
}

// Round 17
// 194.840 us; speedup vs baseline: 1.0752x; 1.0355x over previous
//
#include <hip/hip_runtime.h>
#include <hip/hip_bf16.h>

typedef _Float16 half_t;
typedef _Float16 f16x8 __attribute__((ext_vector_type(8)));
typedef float f32x4 __attribute__((ext_vector_type(4)));

#define AS1 __attribute__((address_space(1)))
#define AS3 __attribute__((address_space(3)))

constexpr int CB = 512;    // channels
constexpr int NB = 2048;   // sequence length
constexpr int BB = 8;      // batch

__device__ inline f32x4 mfma16(f16x8 a, f16x8 b, f32x4 c) {
  return __builtin_amdgcn_mfma_f32_16x16x32_f16(a, b, c, 0, 0, 0);
}

// T1: XCD-aware bijective block remap (requires nwg % 8 == 0; else identity)
__device__ inline void xcd_swizzle(int& bx, int& by, int& bz) {
  const int gx = gridDim.x, gy = gridDim.y, gz = gridDim.z;
  const int nwg = gx * gy * gz;
  int lin = blockIdx.x + gx * (blockIdx.y + gy * blockIdx.z);
  if ((nwg & 7) == 0) {
    const int q = nwg >> 3;
    lin = (lin & 7) * q + (lin >> 3);
  }
  bx = lin % gx;
  int tmp = lin / gx;
  by = tmp % gy;
  bz = tmp / gy;
}

// ================ merged preprocessing stage 1 ================
__global__ __launch_bounds__(256) void prep_all(
    const float* __restrict__ x, const float* __restrict__ wq,
    const float* __restrict__ wk, const float* __restrict__ wv,
    const float* __restrict__ bq,
    half_t* __restrict__ xh, half_t* __restrict__ xn,
    half_t* __restrict__ wvh, float* __restrict__ u, float* __restrict__ Gp) {
  __shared__ float smem[64 * 68 * 2];
  const int b = blockIdx.x;
  const int t = threadIdx.x;

  if (b < 8192) {
    float (*tile)[33] = (float(*)[33])smem;
    const int bz = b >> 10, by = (b >> 6) & 15, bx = b & 63;
    const int c0 = by * 32, n0 = bx * 32;
    const int tx = t & 31, ty = t >> 5;
    const float* xb = x + (size_t)bz * CB * NB;
    half_t* xnb = xn + (size_t)bz * CB * NB;
#pragma unroll
    for (int r = 0; r < 4; r++) {
      float v = xb[(size_t)(c0 + ty + 8 * r) * NB + n0 + tx];
      tile[ty + 8 * r][tx] = v;
      xnb[(size_t)(c0 + ty + 8 * r) * NB + n0 + tx] = (half_t)v;
    }
    __syncthreads();
    size_t base = (size_t)bz * NB * CB;
#pragma unroll
    for (int r = 0; r < 4; r++)
      xh[base + (size_t)(n0 + ty + 8 * r) * CB + c0 + tx] = (half_t)tile[tx][ty + 8 * r];
  } else if (b < 8704) {
    const int g = b - 8192;
    const int d0 = (g & 7) * 64, c0 = ((g >> 3) & 7) * 64, o0 = (g >> 6) * 64;
    float (*aq)[68] = (float(*)[68])smem;
    float (*ak)[68] = (float(*)[68])(smem + 64 * 68);
    {
      const int r = t >> 2, cbase = (t & 3) * 16;
      const float* q = wq + (size_t)(o0 + r) * CB + c0 + cbase;
      const float* k = wk + (size_t)(o0 + r) * CB + d0 + cbase;
#pragma unroll
      for (int q4 = 0; q4 < 4; q4++) {
        *(float4*)&aq[r][cbase + q4 * 4] = *(const float4*)(q + q4 * 4);
        *(float4*)&ak[r][cbase + q4 * 4] = *(const float4*)(k + q4 * 4);
      }
    }
    __syncthreads();
    const int tc = t & 15, td = t >> 4;
    float acc[4][4] = {};
#pragma unroll 8
    for (int o = 0; o < 64; o++) {
      float4 a4 = *(const float4*)&aq[o][tc * 4];
      float4 b4 = *(const float4*)&ak[o][td * 4];
      float av[4] = {a4.x, a4.y, a4.z, a4.w};
      float bv[4] = {b4.x, b4.y, b4.z, b4.w};
#pragma unroll
      for (int i = 0; i < 4; i++)
#pragma unroll
        for (int j = 0; j < 4; j++)
          acc[i][j] += av[i] * bv[j];
    }
    float* gz = Gp + (size_t)(g >> 6) * CB * CB;
#pragma unroll
    for (int i = 0; i < 4; i++) {
      int c = c0 + tc * 4 + i;
#pragma unroll
      for (int j = 0; j < 4; j++)
        gz[(size_t)c * CB + d0 + td * 4 + j] = acc[i][j];
    }
  } else {
    const int p = b - 8704;
    if (p < 1024) {
      int i = p * 256 + t;
      if (i < CB * CB) wvh[i] = (half_t)wv[i];
    } else {
      int d = (p - 1024) * 256 + t;
      if (d < CB) {
        float s = 0.0f;
        for (int o = 0; o < CB; o++) s += bq[o] * wk[(size_t)o * CB + d];
        u[d] = s;
      }
    }
  }
}

// ================ merged preprocessing stage 2 ================
__global__ __launch_bounds__(256) void prep2(
    const float* __restrict__ Gp, half_t* __restrict__ Gh,
    const half_t* __restrict__ xh, const float* __restrict__ u,
    float* __restrict__ ub) {
  const int b = blockIdx.x;
  const int t = threadIdx.x;
  if (b < 1024) {
    int i = b * 256 + t;
    if (i < CB * CB) {
      float s = 0.0f;
#pragma unroll
      for (int z = 0; z < 8; z++) s += Gp[(size_t)z * CB * CB + i];
      Gh[i] = (half_t)s;
    }
  } else {
    __shared__ float us[CB];
    for (int i = t; i < CB; i += 256) us[i] = u[i];
    __syncthreads();
    int row = (b - 1024) * 4 + (t >> 6);
    int lane = t & 63;
    f16x8 vh = *(const f16x8*)(xh + (size_t)row * CB + lane * 8);
    float s = 0.0f;
#pragma unroll
    for (int i = 0; i < 8; i++) s += us[lane * 8 + i] * (float)vh[i];
#pragma unroll
    for (int off = 32; off; off >>= 1) s += __shfl_xor(s, off);
    if (lane == 0) ub[row] = s;
  }
}

// ================ NEW: S-GEMM 256^2, 2-phase-per-K-tile, 3-buffer counted-vmcnt ========
// S[z][i][j] = sum_c xh[z][i][c]*YTh[z][j][c] + ub[z][j] -> int16 (scale 256)
// 512 thr, 8 waves (2M x 4N), per-wave C 128x64 (acc[8][4]); BK=32, NT=16; LDS 3x32KB.
// Race analysis: stage(kt+2)->buf[(rb+2)%3], last read at kt-1 (two barriers back);
// reads of buf[rb] are consumed by same-phase MFMAs before the next barrier;
// vmcnt(4) at tile end leaves only kt+1's 4 loads in flight (kt+2's data not yet needed).
__global__ __launch_bounds__(512) void gemm_s256(
    const half_t* __restrict__ xh, const half_t* __restrict__ YTh,
    short* __restrict__ Ss, const float* __restrict__ ub) {
  constexpr int NT = 16;
  constexpr int BUFE = 16384;                 // elems: A 8192 + B 8192
  __shared__ alignas(16) half_t sm[3 * BUFE]; // 96 KB

  int bxi, byi, bzi;
  xcd_swizzle(bxi, byi, bzi);
  const int t = threadIdx.x;
  const int z = bzi;
  const half_t* Ap = xh  + (size_t)z * NB * CB + (size_t)(byi * 256) * CB;
  const half_t* Bp = YTh + (size_t)z * NB * CB + (size_t)(bxi * 256) * CB;

  const int wid = t >> 6, wm = wid >> 2, wn = wid & 3;
  const int l15 = t & 15, hi = (t >> 4) & 3;
  const int sr = t >> 2, sc = (t & 3) * 8;    // staging row 0..127, col chunk

  f32x4 acc[8][4] = {};

  auto stageA = [&](int buf, int kt) {
    half_t* dst = sm + buf * BUFE;
#pragma unroll
    for (int i = 0; i < 2; i++)
      __builtin_amdgcn_global_load_lds(
          (const AS1 void*)(Ap + (size_t)(i * 128 + sr) * CB + kt * 32 + sc),
          (AS3 void*)(dst + i * 4096 + t * 8), 16, 0, 0);
  };
  auto stageB = [&](int buf, int kt) {
    half_t* dst = sm + buf * BUFE + 8192;
#pragma unroll
    for (int i = 0; i < 2; i++)
      __builtin_amdgcn_global_load_lds(
          (const AS1 void*)(Bp + (size_t)(i * 128 + sr) * CB + kt * 32 + sc),
          (AS3 void*)(dst + i * 4096 + t * 8), 16, 0, 0);
  };

  // prologue: K-tiles 0,1 in flight; wait K-tile 0 (oldest 4 loads)
  stageA(0, 0); stageB(0, 0);
  stageA(1, 1); stageB(1, 1);
  asm volatile("s_waitcnt vmcnt(4)" ::: "memory");
  __builtin_amdgcn_s_barrier();
  asm volatile("" ::: "memory");

  int rb = 0;
  for (int kt = 0; kt < NT; kt++) {
    const half_t* Abuf = sm + rb * BUFE;
    const half_t* Bbuf = Abuf + 8192;
    const int sb = (rb + 2 >= 3) ? rb - 1 : rb + 2;

    // ---- phase 1: reads (af[0..3] + bf[0..3]) || stage A(kt+2) || 16 MFMA
    f16x8 af[8], bf[4];
#pragma unroll
    for (int f = 0; f < 4; f++)
      af[f] = *(const f16x8*)(Abuf + (wm * 128 + f * 16 + l15) * 32 + hi * 8);
#pragma unroll
    for (int n = 0; n < 4; n++)
      bf[n] = *(const f16x8*)(Bbuf + (wn * 64 + n * 16 + l15) * 32 + hi * 8);
    if (kt + 2 < NT) stageA(sb, kt + 2);
    __builtin_amdgcn_s_barrier();
    asm volatile("s_waitcnt lgkmcnt(0)" ::: "memory");
    __builtin_amdgcn_s_setprio(1);
#pragma unroll
    for (int m = 0; m < 4; m++)
#pragma unroll
      for (int n = 0; n < 4; n++)
        acc[m][n] = mfma16(af[m], bf[n], acc[m][n]);
    __builtin_amdgcn_s_setprio(0);
    __builtin_amdgcn_s_barrier();
    asm volatile("" ::: "memory");

    // ---- phase 2: reads (af[4..7]) || stage B(kt+2) || 16 MFMA
#pragma unroll
    for (int f = 4; f < 8; f++)
      af[f] = *(const f16x8*)(Abuf + (wm * 128 + f * 16 + l15) * 32 + hi * 8);
    if (kt + 2 < NT) stageB(sb, kt + 2);
    __builtin_amdgcn_s_barrier();
    asm volatile("s_waitcnt lgkmcnt(0)" ::: "memory");
    __builtin_amdgcn_s_setprio(1);
#pragma unroll
    for (int m = 4; m < 8; m++)
#pragma unroll
      for (int n = 0; n < 4; n++)
        acc[m][n] = mfma16(af[m], bf[n], acc[m][n]);
    __builtin_amdgcn_s_setprio(0);
    // ---- K-tile end: counted wait (next tile's loads retired), publish
    if (kt + 1 < NT) {
      if (kt + 2 < NT) asm volatile("s_waitcnt vmcnt(4)" ::: "memory");
      else             asm volatile("s_waitcnt vmcnt(0)" ::: "memory");
    }
    __builtin_amdgcn_s_barrier();
    asm volatile("" ::: "memory");
    rb = (rb + 1 == 3) ? 0 : rb + 1;
  }

  const int row0 = byi * 256 + wm * 128;
  const int col0 = bxi * 256 + wn * 64;
  short* Sz = Ss + (size_t)z * NB * NB;
  const float* ubz = ub + (size_t)z * NB;
#pragma unroll
  for (int m = 0; m < 8; m++) {
    int rowb = row0 + m * 16 + hi * 4;
#pragma unroll
    for (int n = 0; n < 4; n++) {
      int col = col0 + n * 16 + l15;
      float bc = ubz[col];
#pragma unroll
      for (int r = 0; r < 4; r++) {
        float sv = fminf(fmaxf((acc[m][n][r] + bc) * 256.0f, -32767.0f), 32767.0f);
        Sz[(size_t)(rowb + r) * NB + col] = (short)__float2int_rn(sv);
      }
    }
  }
}

// ---------------- GEMM-NT (proven 128^2 2-barrier, fp16) + T1 swizzle — used for PV
// BIAS: 0 none, 1 batched col-bias. EPI: 3 f32 + fp16 residual R; 4 int16 fixed-point
template <int BIAS, int EPI, int NT>
__global__ __launch_bounds__(256) void gemm_nt(
    const half_t* __restrict__ A, int lda, long sA,
    const half_t* __restrict__ Bh, int ldb, long sB,
    void* __restrict__ D, int ldd, long sD,
    const float* __restrict__ bias, long sBias,
    const half_t* __restrict__ R, int ldr, long sR) {
  constexpr int TSZ = 128 * 32;
  __shared__ alignas(16) half_t sm[2 * 2 * TSZ];

  int bxi, byi, bzi;
  xcd_swizzle(bxi, byi, bzi);
  const int t = threadIdx.x;
  const int z = bzi;
  const half_t* Ab  = A  + (size_t)z * sA + (size_t)(byi * 128) * lda;
  const half_t* Bbh = Bh + (size_t)z * sB + (size_t)(bxi * 128) * ldb;
  const int wid = t >> 6, l15 = t & 15, hi = (t >> 4) & 3;
  const int wr = wid >> 1, wc = wid & 1;
  const int lineA = t >> 2, eoff = (t & 3) * 8;

  f32x4 acc[4][4] = {};

  auto stage = [&](int buf, int kt) {
    half_t* base = sm + buf * (2 * TSZ);
#pragma unroll
    for (int p = 0; p < 2; p++) {
      size_t goA = (size_t)(p * 64 + lineA) * lda + kt * 32 + eoff;
      size_t goB = (size_t)(p * 64 + lineA) * ldb + kt * 32 + eoff;
      int lo = p * 2048 + t * 8;
      __builtin_amdgcn_global_load_lds((const AS1 void*)(Ab + goA),  (AS3 void*)(base + lo), 16, 0, 0);
      __builtin_amdgcn_global_load_lds((const AS1 void*)(Bbh + goB), (AS3 void*)(base + TSZ + lo), 16, 0, 0);
    }
  };

  stage(0, 0);
  __syncthreads();
  int cur = 0;
  for (int kt = 0; kt < NT; kt++) {
    if (kt + 1 < NT) stage(cur ^ 1, kt + 1);
    const half_t* bb = sm + cur * (2 * TSZ);
    f16x8 af[4], bf[4];
#pragma unroll
    for (int f = 0; f < 4; f++) {
      af[f] = *(const f16x8*)(bb + (wr * 64 + f * 16 + l15) * 32 + hi * 8);
      bf[f] = *(const f16x8*)(bb + TSZ + (wc * 64 + f * 16 + l15) * 32 + hi * 8);
    }
#pragma unroll
    for (int fm = 0; fm < 4; fm++)
#pragma unroll
      for (int fn = 0; fn < 4; fn++)
        acc[fm][fn] = mfma16(af[fm], bf[fn], acc[fm][fn]);
    __syncthreads();
    cur ^= 1;
  }

  const int row0 = byi * 128 + wr * 64;
  const int col0 = bxi * 128 + wc * 64;
#pragma unroll
  for (int fm = 0; fm < 4; fm++) {
    int rowb = row0 + fm * 16 + hi * 4;
#pragma unroll
    for (int fn = 0; fn < 4; fn++) {
      int col = col0 + fn * 16 + l15;
      float bc = (BIAS == 1) ? bias[(size_t)z * sBias + col] : 0.0f;
#pragma unroll
      for (int r = 0; r < 4; r++) {
        float val = acc[fm][fn][r] + bc;
        size_t di = (size_t)(rowb + r) * ldd + col;
        if (EPI == 3) {
          val += (float)R[(size_t)z * sR + (size_t)(rowb + r) * ldr + col];
          ((float*)D)[(size_t)z * sD + di] = val;
        } else {
          float sv = fminf(fmaxf(val * 256.0f, -32767.0f), 32767.0f);
          ((short*)D)[(size_t)z * sD + di] = (short)__float2int_rn(sv);
        }
      }
    }
  }
}

// ---------------- merged YT + V GEMM (one dispatch, grid (16,4,16))
__global__ __launch_bounds__(256) void gemm_vyt(
    const half_t* __restrict__ xh, const half_t* __restrict__ wvh,
    const half_t* __restrict__ Gh, const float* __restrict__ bv,
    half_t* __restrict__ v, half_t* __restrict__ YTh) {
  constexpr int TSZ = 128 * 32;
  __shared__ alignas(16) half_t sm[2 * 2 * TSZ];

  int bxi, byi, bzi;
  xcd_swizzle(bxi, byi, bzi);
  const int t = threadIdx.x;

  const half_t* Ab;
  const half_t* Bb;
  half_t* Dz;
  int ldd, row0b, col0b;
  const float* rowbias = nullptr;
  if (bzi < 8) {           // V-mode
    const int z = bzi;
    Ab = wvh + (size_t)(byi * 128) * CB;
    Bb = xh + (size_t)z * NB * CB + (size_t)(bxi * 128) * CB;
    Dz = v + (size_t)z * CB * NB;
    ldd = NB; row0b = byi * 128; col0b = bxi * 128;
    rowbias = bv;
  } else {                 // YT-mode
    const int z = bzi - 8;
    const int lin2 = byi * 16 + bxi;        // [0,64)
    const int xp = lin2 & 3, yp = lin2 >> 2;
    Ab = xh + (size_t)z * NB * CB + (size_t)(yp * 128) * CB;
    Bb = Gh + (size_t)(xp * 128) * CB;
    Dz = YTh + (size_t)z * NB * CB;
    ldd = CB; row0b = yp * 128; col0b = xp * 128;
  }

  const int wid = t >> 6, l15 = t & 15, hi = (t >> 4) & 3;
  const int wr = wid >> 1, wc = wid & 1;
  const int lineA = t >> 2, eoff = (t & 3) * 8;

  f32x4 acc[4][4] = {};

  auto stage = [&](int buf, int kt) {
    half_t* base = sm + buf * (2 * TSZ);
#pragma unroll
    for (int p = 0; p < 2; p++) {
      size_t go = (size_t)(p * 64 + lineA) * CB + kt * 32 + eoff;
      int lo = p * 2048 + t * 8;
      __builtin_amdgcn_global_load_lds((const AS1 void*)(Ab + go), (AS3 void*)(base + lo), 16, 0, 0);
      __builtin_amdgcn_global_load_lds((const AS1 void*)(Bb + go), (AS3 void*)(base + TSZ + lo), 16, 0, 0);
    }
  };

  stage(0, 0);
  __syncthreads();
  int cur = 0;
  for (int kt = 0; kt < 16; kt++) {
    if (kt + 1 < 16) stage(cur ^ 1, kt + 1);
    const half_t* bb = sm + cur * (2 * TSZ);
    f16x8 af[4], bf[4];
#pragma unroll
    for (int f = 0; f < 4; f++) {
      af[f] = *(const f16x8*)(bb + (wr * 64 + f * 16 + l15) * 32 + hi * 8);
      bf[f] = *(const f16x8*)(bb + TSZ + (wc * 64 + f * 16 + l15) * 32 + hi * 8);
    }
#pragma unroll
    for (int fm = 0; fm < 4; fm++)
#pragma unroll
      for (int fn = 0; fn < 4; fn++)
        acc[fm][fn] = mfma16(af[fm], bf[fn], acc[fm][fn]);
    __syncthreads();
    cur ^= 1;
  }

  const int row0 = row0b + wr * 64;
  const int col0 = col0b + wc * 64;
#pragma unroll
  for (int fm = 0; fm < 4; fm++) {
    int rowb = row0 + fm * 16 + hi * 4;
#pragma unroll
    for (int fn = 0; fn < 4; fn++) {
      int col = col0 + fn * 16 + l15;
#pragma unroll
      for (int r = 0; r < 4; r++) {
        float val = acc[fm][fn][r];
        if (rowbias) val += rowbias[rowb + r];
        Dz[(size_t)(rowb + r) * ldd + col] = (half_t)val;
      }
    }
  }
}

// ---------------- row softmax over S int16 [rows][2048] (scale 1/256); writes dense P fp16
struct alignas(16) H8 { half_t h[8]; };
struct alignas(16) S8 { short s[8]; };

__global__ __launch_bounds__(256) void softmax_rows(const short* __restrict__ S,
                                                    half_t* __restrict__ P) {
  const short* row = S + (size_t)blockIdx.x * NB;
  int t = threadIdx.x;
  S8 r8 = *reinterpret_cast<const S8*>(row + t * 8);
  float vals[8];
#pragma unroll
  for (int i = 0; i < 8; i++) vals[i] = (float)r8.s[i] * 0.00390625f;
  float m = vals[0];
#pragma unroll
  for (int i = 1; i < 8; i++) m = fmaxf(m, vals[i]);
#pragma unroll
  for (int off = 32; off; off >>= 1) m = fmaxf(m, __shfl_xor(m, off));
  __shared__ float redm[4], reds[4];
  if ((t & 63) == 0) redm[t >> 6] = m;
  __syncthreads();
  m = fmaxf(fmaxf(redm[0], redm[1]), fmaxf(redm[2], redm[3]));
  float e[8], s = 0.0f;
#pragma unroll
  for (int i = 0; i < 8; i++) { e[i] = __expf(vals[i] - m); s += e[i]; }
#pragma unroll
  for (int off = 32; off; off >>= 1) s += __shfl_xor(s, off);
  if ((t & 63) == 0) reds[t >> 6] = s;
  __syncthreads();
  s = reds[0] + reds[1] + reds[2] + reds[3];
  float inv = 1.0f / s;
  H8 ob;
#pragma unroll
  for (int i = 0; i < 8; i++) ob.h[i] = (half_t)(e[i] * inv);
  *reinterpret_cast<H8*>(P + (size_t)blockIdx.x * NB + t * 8) = ob;
}

// ---------------- launcher
extern "C" void kernel_launch(void* const* d_in, const int* in_sizes, int n_in,
                              void* d_out, int out_size, void* d_ws, size_t ws_size,
                              hipStream_t stream) {
  const float* x  = (const float*)d_in[0];
  const float* wq = (const float*)d_in[1];
  const float* bq = (const float*)d_in[2];
  const float* wk = (const float*)d_in[3];
  const float* wv = (const float*)d_in[5];
  const float* bv = (const float*)d_in[6];
  float* out = (float*)d_out;

  const size_t MB = 1u << 20;
  if (ws_size < 196 * MB) return;

  char* ws = (char*)d_ws;
  half_t* xh   = (half_t*)(ws + 0);            // [B][N][C]    16 MB
  half_t* YTh  = (half_t*)(ws + 16 * MB);      // [B][N][C]    16 MB
  half_t* v    = (half_t*)(ws + 32 * MB);      // [B][C][N]    16 MB
  short*  Ss   = (short*)(ws + 48 * MB);       // [8][N][N]    64 MB (int16 logits, scale 256)
  float*  Gp   = (float*)(ws + 48 * MB);       // [8][C][C]     8 MB (overlay; dead before S)
  half_t* Pd   = (half_t*)(ws + 112 * MB);     // [8][N][N]    64 MB (dense P)
  half_t* xn   = (half_t*)(ws + 176 * MB);     // [B][C][N]    16 MB (fp16 residual copy)
  half_t* Gh   = (half_t*)(ws + 192 * MB);     // [C][C]      0.5 MB
  half_t* wvh  = (half_t*)(ws + 192 * MB + 512 * 1024);  // [C][C]  0.5 MB
  float*  u    = (float*)(ws + 193 * MB);                // [C]       2 KB
  float*  ub   = (float*)(ws + 193 * MB + 256 * 1024);   // [B][N]   64 KB

  prep_all<<<9730, 256, 0, stream>>>(x, wq, wk, wv, bq, xh, xn, wvh, u, Gp);
  prep2<<<5120, 256, 0, stream>>>(Gp, Gh, xh, u, ub);

  gemm_vyt<<<dim3(16, 4, 16), 256, 0, stream>>>(xh, wvh, Gh, bv, v, YTh);

  // S: new 256^2 phase-split kernel
  gemm_s256<<<dim3(8, 8, 8), 512, 0, stream>>>(xh, YTh, Ss, ub);

  softmax_rows<<<BB * NB, 256, 0, stream>>>(Ss, Pd);

  // out[z][ch][i] = sum_j v[z][ch][j]*Pd[z][i][j] + xn[z][ch][i]   (proven kernel)
  gemm_nt<0, 3, 64><<<dim3(16, 4, 8), 256, 0, stream>>>(
      v, NB, (long)CB * NB,
      Pd, NB, (long)NB * NB,
      out, NB, (long)CB * NB, nullptr, 0,
      xn, NB, (long)CB * NB);
}

// Round 18
// 188.319 us; speedup vs baseline: 1.1125x; 1.0346x over previous
//
#include <hip/hip_runtime.h>
#include <hip/hip_bf16.h>

typedef _Float16 half_t;
typedef _Float16 f16x8 __attribute__((ext_vector_type(8)));
typedef float f32x4 __attribute__((ext_vector_type(4)));

#define AS1 __attribute__((address_space(1)))
#define AS3 __attribute__((address_space(3)))

constexpr int CB = 512;    // channels
constexpr int NB = 2048;   // sequence length
constexpr int BB = 8;      // batch

__device__ inline f32x4 mfma16(f16x8 a, f16x8 b, f32x4 c) {
  return __builtin_amdgcn_mfma_f32_16x16x32_f16(a, b, c, 0, 0, 0);
}

// T1: XCD-aware bijective block remap (requires nwg % 8 == 0; else identity)
__device__ inline void xcd_swizzle(int& bx, int& by, int& bz) {
  const int gx = gridDim.x, gy = gridDim.y, gz = gridDim.z;
  const int nwg = gx * gy * gz;
  int lin = blockIdx.x + gx * (blockIdx.y + gy * blockIdx.z);
  if ((nwg & 7) == 0) {
    const int q = nwg >> 3;
    lin = (lin & 7) * q + (lin >> 3);
  }
  bx = lin % gx;
  int tmp = lin / gx;
  by = tmp % gy;
  bz = tmp / gy;
}

// ================ merged preprocessing stage 1 ================
__global__ __launch_bounds__(256) void prep_all(
    const float* __restrict__ x, const float* __restrict__ wq,
    const float* __restrict__ wk, const float* __restrict__ wv,
    const float* __restrict__ bq,
    half_t* __restrict__ xh, half_t* __restrict__ xn,
    half_t* __restrict__ wvh, float* __restrict__ u, float* __restrict__ Gp) {
  __shared__ float smem[64 * 68 * 2];
  const int b = blockIdx.x;
  const int t = threadIdx.x;

  if (b < 8192) {
    float (*tile)[33] = (float(*)[33])smem;
    const int bz = b >> 10, by = (b >> 6) & 15, bx = b & 63;
    const int c0 = by * 32, n0 = bx * 32;
    const int tx = t & 31, ty = t >> 5;
    const float* xb = x + (size_t)bz * CB * NB;
    half_t* xnb = xn + (size_t)bz * CB * NB;
#pragma unroll
    for (int r = 0; r < 4; r++) {
      float v = xb[(size_t)(c0 + ty + 8 * r) * NB + n0 + tx];
      tile[ty + 8 * r][tx] = v;
      xnb[(size_t)(c0 + ty + 8 * r) * NB + n0 + tx] = (half_t)v;
    }
    __syncthreads();
    size_t base = (size_t)bz * NB * CB;
#pragma unroll
    for (int r = 0; r < 4; r++)
      xh[base + (size_t)(n0 + ty + 8 * r) * CB + c0 + tx] = (half_t)tile[tx][ty + 8 * r];
  } else if (b < 8704) {
    const int g = b - 8192;
    const int d0 = (g & 7) * 64, c0 = ((g >> 3) & 7) * 64, o0 = (g >> 6) * 64;
    float (*aq)[68] = (float(*)[68])smem;
    float (*ak)[68] = (float(*)[68])(smem + 64 * 68);
    {
      const int r = t >> 2, cbase = (t & 3) * 16;
      const float* q = wq + (size_t)(o0 + r) * CB + c0 + cbase;
      const float* k = wk + (size_t)(o0 + r) * CB + d0 + cbase;
#pragma unroll
      for (int q4 = 0; q4 < 4; q4++) {
        *(float4*)&aq[r][cbase + q4 * 4] = *(const float4*)(q + q4 * 4);
        *(float4*)&ak[r][cbase + q4 * 4] = *(const float4*)(k + q4 * 4);
      }
    }
    __syncthreads();
    const int tc = t & 15, td = t >> 4;
    float acc[4][4] = {};
#pragma unroll 8
    for (int o = 0; o < 64; o++) {
      float4 a4 = *(const float4*)&aq[o][tc * 4];
      float4 b4 = *(const float4*)&ak[o][td * 4];
      float av[4] = {a4.x, a4.y, a4.z, a4.w};
      float bv[4] = {b4.x, b4.y, b4.z, b4.w};
#pragma unroll
      for (int i = 0; i < 4; i++)
#pragma unroll
        for (int j = 0; j < 4; j++)
          acc[i][j] += av[i] * bv[j];
    }
    float* gz = Gp + (size_t)(g >> 6) * CB * CB;
#pragma unroll
    for (int i = 0; i < 4; i++) {
      int c = c0 + tc * 4 + i;
#pragma unroll
      for (int j = 0; j < 4; j++)
        gz[(size_t)c * CB + d0 + td * 4 + j] = acc[i][j];
    }
  } else {
    const int p = b - 8704;
    if (p < 1024) {
      int i = p * 256 + t;
      if (i < CB * CB) wvh[i] = (half_t)wv[i];
    } else {
      int d = (p - 1024) * 256 + t;
      if (d < CB) {
        float s = 0.0f;
        for (int o = 0; o < CB; o++) s += bq[o] * wk[(size_t)o * CB + d];
        u[d] = s;
      }
    }
  }
}

// ================ merged preprocessing stage 2 ================
__global__ __launch_bounds__(256) void prep2(
    const float* __restrict__ Gp, half_t* __restrict__ Gh,
    const half_t* __restrict__ xh, const float* __restrict__ u,
    float* __restrict__ ub) {
  const int b = blockIdx.x;
  const int t = threadIdx.x;
  if (b < 1024) {
    int i = b * 256 + t;
    if (i < CB * CB) {
      float s = 0.0f;
#pragma unroll
      for (int z = 0; z < 8; z++) s += Gp[(size_t)z * CB * CB + i];
      Gh[i] = (half_t)s;
    }
  } else {
    __shared__ float us[CB];
    for (int i = t; i < CB; i += 256) us[i] = u[i];
    __syncthreads();
    int row = (b - 1024) * 4 + (t >> 6);
    int lane = t & 63;
    f16x8 vh = *(const f16x8*)(xh + (size_t)row * CB + lane * 8);
    float s = 0.0f;
#pragma unroll
    for (int i = 0; i < 8; i++) s += us[lane * 8 + i] * (float)vh[i];
#pragma unroll
    for (int off = 32; off; off >>= 1) s += __shfl_xor(s, off);
    if (lane == 0) ub[row] = s;
  }
}

// ================ S-GEMM 256^2, 2-phase, 3-buffer counted-vmcnt (proven r17) ========
__global__ __launch_bounds__(512) void gemm_s256(
    const half_t* __restrict__ xh, const half_t* __restrict__ YTh,
    short* __restrict__ Ss, const float* __restrict__ ub) {
  constexpr int NT = 16;
  constexpr int BUFE = 16384;
  __shared__ alignas(16) half_t sm[3 * BUFE]; // 96 KB

  int bxi, byi, bzi;
  xcd_swizzle(bxi, byi, bzi);
  const int t = threadIdx.x;
  const int z = bzi;
  const half_t* Ap = xh  + (size_t)z * NB * CB + (size_t)(byi * 256) * CB;
  const half_t* Bp = YTh + (size_t)z * NB * CB + (size_t)(bxi * 256) * CB;

  const int wid = t >> 6, wm = wid >> 2, wn = wid & 3;
  const int l15 = t & 15, hi = (t >> 4) & 3;
  const int sr = t >> 2, sc = (t & 3) * 8;

  f32x4 acc[8][4] = {};

  auto stageA = [&](int buf, int kt) {
    half_t* dst = sm + buf * BUFE;
#pragma unroll
    for (int i = 0; i < 2; i++)
      __builtin_amdgcn_global_load_lds(
          (const AS1 void*)(Ap + (size_t)(i * 128 + sr) * CB + kt * 32 + sc),
          (AS3 void*)(dst + i * 4096 + t * 8), 16, 0, 0);
  };
  auto stageB = [&](int buf, int kt) {
    half_t* dst = sm + buf * BUFE + 8192;
#pragma unroll
    for (int i = 0; i < 2; i++)
      __builtin_amdgcn_global_load_lds(
          (const AS1 void*)(Bp + (size_t)(i * 128 + sr) * CB + kt * 32 + sc),
          (AS3 void*)(dst + i * 4096 + t * 8), 16, 0, 0);
  };

  stageA(0, 0); stageB(0, 0);
  stageA(1, 1); stageB(1, 1);
  asm volatile("s_waitcnt vmcnt(4)" ::: "memory");
  __builtin_amdgcn_s_barrier();
  asm volatile("" ::: "memory");

  int rb = 0;
  for (int kt = 0; kt < NT; kt++) {
    const half_t* Abuf = sm + rb * BUFE;
    const half_t* Bbuf = Abuf + 8192;
    const int sb = (rb + 2 >= 3) ? rb - 1 : rb + 2;

    f16x8 af[8], bf[4];
#pragma unroll
    for (int f = 0; f < 4; f++)
      af[f] = *(const f16x8*)(Abuf + (wm * 128 + f * 16 + l15) * 32 + hi * 8);
#pragma unroll
    for (int n = 0; n < 4; n++)
      bf[n] = *(const f16x8*)(Bbuf + (wn * 64 + n * 16 + l15) * 32 + hi * 8);
    if (kt + 2 < NT) stageA(sb, kt + 2);
    __builtin_amdgcn_s_barrier();
    asm volatile("s_waitcnt lgkmcnt(0)" ::: "memory");
    __builtin_amdgcn_s_setprio(1);
#pragma unroll
    for (int m = 0; m < 4; m++)
#pragma unroll
      for (int n = 0; n < 4; n++)
        acc[m][n] = mfma16(af[m], bf[n], acc[m][n]);
    __builtin_amdgcn_s_setprio(0);
    __builtin_amdgcn_s_barrier();
    asm volatile("" ::: "memory");

#pragma unroll
    for (int f = 4; f < 8; f++)
      af[f] = *(const f16x8*)(Abuf + (wm * 128 + f * 16 + l15) * 32 + hi * 8);
    if (kt + 2 < NT) stageB(sb, kt + 2);
    __builtin_amdgcn_s_barrier();
    asm volatile("s_waitcnt lgkmcnt(0)" ::: "memory");
    __builtin_amdgcn_s_setprio(1);
#pragma unroll
    for (int m = 4; m < 8; m++)
#pragma unroll
      for (int n = 0; n < 4; n++)
        acc[m][n] = mfma16(af[m], bf[n], acc[m][n]);
    __builtin_amdgcn_s_setprio(0);
    if (kt + 1 < NT) {
      if (kt + 2 < NT) asm volatile("s_waitcnt vmcnt(4)" ::: "memory");
      else             asm volatile("s_waitcnt vmcnt(0)" ::: "memory");
    }
    __builtin_amdgcn_s_barrier();
    asm volatile("" ::: "memory");
    rb = (rb + 1 == 3) ? 0 : rb + 1;
  }

  const int row0 = byi * 256 + wm * 128;
  const int col0 = bxi * 256 + wn * 64;
  short* Sz = Ss + (size_t)z * NB * NB;
  const float* ubz = ub + (size_t)z * NB;
#pragma unroll
  for (int m = 0; m < 8; m++) {
    int rowb = row0 + m * 16 + hi * 4;
#pragma unroll
    for (int n = 0; n < 4; n++) {
      int col = col0 + n * 16 + l15;
      float bc = ubz[col];
#pragma unroll
      for (int r = 0; r < 4; r++) {
        float sv = fminf(fmaxf((acc[m][n][r] + bc) * 256.0f, -32767.0f), 32767.0f);
        Sz[(size_t)(rowb + r) * NB + col] = (short)__float2int_rn(sv);
      }
    }
  }
}

// ================ NEW: PV GEMM on the s256 schedule, 128x256 tile, 64-K super-tiles ====
// out[z][ch][i] = sum_j v[z][ch][j]*Pd[z][i][j] + xn[z][ch][i]
// 512 thr, 8 waves (2M x 4N), per-wave 64x64 (acc[4][4]); super-tile = 64 K-cols stored
// as [ks][rows][32] (row stride 64B, conflict class unchanged). 3 x 48KB buffers.
// vmcnt ledger: 6 issues/super, 2 supers in flight -> vmcnt(6) at super end.
__global__ __launch_bounds__(512) void gemm_pv256(
    const half_t* __restrict__ V, const half_t* __restrict__ Pd,
    const half_t* __restrict__ xn, float* __restrict__ out) {
  constexpr int NSUP = 32;                      // K = 2048 / 64
  constexpr int BUFE = 24576;                   // A 2*4096 + B 2*8192 elems (48 KB)
  __shared__ alignas(16) half_t sm[3 * BUFE];   // 144 KB

  int bxi, byi, bzi;
  xcd_swizzle(bxi, byi, bzi);
  const int t = threadIdx.x, z = bzi;
  const half_t* Ap = V  + (size_t)z * CB * NB + (size_t)(byi * 128) * NB;
  const half_t* Bp = Pd + (size_t)z * NB * NB + (size_t)(bxi * 256) * NB;

  const int wid = t >> 6, wm = wid >> 2, wn = wid & 3;
  const int l15 = t & 15, hi = (t >> 4) & 3;
  const int sr = t >> 2, sc = (t & 3) * 8;

  f32x4 acc[4][4] = {};

  auto stageA = [&](int buf, int u, int ks) {   // 1 issue: 128 rows x 32 cols
    __builtin_amdgcn_global_load_lds(
        (const AS1 void*)(Ap + (size_t)sr * NB + u * 64 + ks * 32 + sc),
        (AS3 void*)(sm + buf * BUFE + ks * 4096 + t * 8), 16, 0, 0);
  };
  auto stageB = [&](int buf, int u, int ks) {   // 2 issues: 256 rows x 32 cols
    half_t* dst = sm + buf * BUFE + 8192 + ks * 8192;
#pragma unroll
    for (int p = 0; p < 2; p++)
      __builtin_amdgcn_global_load_lds(
          (const AS1 void*)(Bp + (size_t)(p * 128 + sr) * NB + u * 64 + ks * 32 + sc),
          (AS3 void*)(dst + p * 4096 + t * 8), 16, 0, 0);
  };

  // prologue: supers 0,1 in flight (12 issues); wait super 0 (oldest 6)
  stageA(0, 0, 0); stageB(0, 0, 0); stageA(0, 0, 1); stageB(0, 0, 1);
  stageA(1, 1, 0); stageB(1, 1, 0); stageA(1, 1, 1); stageB(1, 1, 1);
  asm volatile("s_waitcnt vmcnt(6)" ::: "memory");
  __builtin_amdgcn_s_barrier();
  asm volatile("" ::: "memory");

  int rb = 0;
  for (int u = 0; u < NSUP; u++) {
    const half_t* Abuf = sm + rb * BUFE;
    const half_t* Bbuf = Abuf + 8192;
    const int sb = (rb + 2 >= 3) ? rb - 1 : rb + 2;
#pragma unroll
    for (int ks = 0; ks < 2; ks++) {
      f16x8 af[4], bf[4];
#pragma unroll
      for (int f = 0; f < 4; f++)
        af[f] = *(const f16x8*)(Abuf + ks * 4096 + (wm * 64 + f * 16 + l15) * 32 + hi * 8);
#pragma unroll
      for (int n = 0; n < 4; n++)
        bf[n] = *(const f16x8*)(Bbuf + ks * 8192 + (wn * 64 + n * 16 + l15) * 32 + hi * 8);
      if (u + 2 < NSUP) { stageA(sb, u + 2, ks); stageB(sb, u + 2, ks); }
      __builtin_amdgcn_s_barrier();
      asm volatile("s_waitcnt lgkmcnt(0)" ::: "memory");
      __builtin_amdgcn_s_setprio(1);
#pragma unroll
      for (int m = 0; m < 4; m++)
#pragma unroll
        for (int n = 0; n < 4; n++)
          acc[m][n] = mfma16(af[m], bf[n], acc[m][n]);
      __builtin_amdgcn_s_setprio(0);
      if (ks == 1 && u + 1 < NSUP) {
        if (u + 2 < NSUP) asm volatile("s_waitcnt vmcnt(6)" ::: "memory");
        else              asm volatile("s_waitcnt vmcnt(0)" ::: "memory");
      }
      __builtin_amdgcn_s_barrier();
      asm volatile("" ::: "memory");
    }
    rb = (rb + 1 == 3) ? 0 : rb + 1;
  }

  const int row0 = byi * 128 + wm * 64;
  const int col0 = bxi * 256 + wn * 64;
  float* Oz = out + (size_t)z * CB * NB;
  const half_t* Rz = xn + (size_t)z * CB * NB;
#pragma unroll
  for (int m = 0; m < 4; m++) {
    int rowb = row0 + m * 16 + hi * 4;
#pragma unroll
    for (int n = 0; n < 4; n++) {
      int col = col0 + n * 16 + l15;
#pragma unroll
      for (int r = 0; r < 4; r++)
        Oz[(size_t)(rowb + r) * NB + col] =
            acc[m][n][r] + (float)Rz[(size_t)(rowb + r) * NB + col];
    }
  }
}

// ---------------- merged YT + V GEMM (one dispatch, grid (16,4,16))
__global__ __launch_bounds__(256) void gemm_vyt(
    const half_t* __restrict__ xh, const half_t* __restrict__ wvh,
    const half_t* __restrict__ Gh, const float* __restrict__ bv,
    half_t* __restrict__ v, half_t* __restrict__ YTh) {
  constexpr int TSZ = 128 * 32;
  __shared__ alignas(16) half_t sm[2 * 2 * TSZ];

  int bxi, byi, bzi;
  xcd_swizzle(bxi, byi, bzi);
  const int t = threadIdx.x;

  const half_t* Ab;
  const half_t* Bb;
  half_t* Dz;
  int ldd, row0b, col0b;
  const float* rowbias = nullptr;
  if (bzi < 8) {           // V-mode
    const int z = bzi;
    Ab = wvh + (size_t)(byi * 128) * CB;
    Bb = xh + (size_t)z * NB * CB + (size_t)(bxi * 128) * CB;
    Dz = v + (size_t)z * CB * NB;
    ldd = NB; row0b = byi * 128; col0b = bxi * 128;
    rowbias = bv;
  } else {                 // YT-mode
    const int z = bzi - 8;
    const int lin2 = byi * 16 + bxi;        // [0,64)
    const int xp = lin2 & 3, yp = lin2 >> 2;
    Ab = xh + (size_t)z * NB * CB + (size_t)(yp * 128) * CB;
    Bb = Gh + (size_t)(xp * 128) * CB;
    Dz = YTh + (size_t)z * NB * CB;
    ldd = CB; row0b = yp * 128; col0b = xp * 128;
  }

  const int wid = t >> 6, l15 = t & 15, hi = (t >> 4) & 3;
  const int wr = wid >> 1, wc = wid & 1;
  const int lineA = t >> 2, eoff = (t & 3) * 8;

  f32x4 acc[4][4] = {};

  auto stage = [&](int buf, int kt) {
    half_t* base = sm + buf * (2 * TSZ);
#pragma unroll
    for (int p = 0; p < 2; p++) {
      size_t go = (size_t)(p * 64 + lineA) * CB + kt * 32 + eoff;
      int lo = p * 2048 + t * 8;
      __builtin_amdgcn_global_load_lds((const AS1 void*)(Ab + go), (AS3 void*)(base + lo), 16, 0, 0);
      __builtin_amdgcn_global_load_lds((const AS1 void*)(Bb + go), (AS3 void*)(base + TSZ + lo), 16, 0, 0);
    }
  };

  stage(0, 0);
  __syncthreads();
  int cur = 0;
  for (int kt = 0; kt < 16; kt++) {
    if (kt + 1 < 16) stage(cur ^ 1, kt + 1);
    const half_t* bb = sm + cur * (2 * TSZ);
    f16x8 af[4], bf[4];
#pragma unroll
    for (int f = 0; f < 4; f++) {
      af[f] = *(const f16x8*)(bb + (wr * 64 + f * 16 + l15) * 32 + hi * 8);
      bf[f] = *(const f16x8*)(bb + TSZ + (wc * 64 + f * 16 + l15) * 32 + hi * 8);
    }
#pragma unroll
    for (int fm = 0; fm < 4; fm++)
#pragma unroll
      for (int fn = 0; fn < 4; fn++)
        acc[fm][fn] = mfma16(af[fm], bf[fn], acc[fm][fn]);
    __syncthreads();
    cur ^= 1;
  }

  const int row0 = row0b + wr * 64;
  const int col0 = col0b + wc * 64;
#pragma unroll
  for (int fm = 0; fm < 4; fm++) {
    int rowb = row0 + fm * 16 + hi * 4;
#pragma unroll
    for (int fn = 0; fn < 4; fn++) {
      int col = col0 + fn * 16 + l15;
#pragma unroll
      for (int r = 0; r < 4; r++) {
        float val = acc[fm][fn][r];
        if (rowbias) val += rowbias[rowb + r];
        Dz[(size_t)(rowb + r) * ldd + col] = (half_t)val;
      }
    }
  }
}

// ---------------- row softmax over S int16 [rows][2048] (scale 1/256); writes dense P fp16
struct alignas(16) H8 { half_t h[8]; };
struct alignas(16) S8 { short s[8]; };

__global__ __launch_bounds__(256) void softmax_rows(const short* __restrict__ S,
                                                    half_t* __restrict__ P) {
  const short* row = S + (size_t)blockIdx.x * NB;
  int t = threadIdx.x;
  S8 r8 = *reinterpret_cast<const S8*>(row + t * 8);
  float vals[8];
#pragma unroll
  for (int i = 0; i < 8; i++) vals[i] = (float)r8.s[i] * 0.00390625f;
  float m = vals[0];
#pragma unroll
  for (int i = 1; i < 8; i++) m = fmaxf(m, vals[i]);
#pragma unroll
  for (int off = 32; off; off >>= 1) m = fmaxf(m, __shfl_xor(m, off));
  __shared__ float redm[4], reds[4];
  if ((t & 63) == 0) redm[t >> 6] = m;
  __syncthreads();
  m = fmaxf(fmaxf(redm[0], redm[1]), fmaxf(redm[2], redm[3]));
  float e[8], s = 0.0f;
#pragma unroll
  for (int i = 0; i < 8; i++) { e[i] = __expf(vals[i] - m); s += e[i]; }
#pragma unroll
  for (int off = 32; off; off >>= 1) s += __shfl_xor(s, off);
  if ((t & 63) == 0) reds[t >> 6] = s;
  __syncthreads();
  s = reds[0] + reds[1] + reds[2] + reds[3];
  float inv = 1.0f / s;
  H8 ob;
#pragma unroll
  for (int i = 0; i < 8; i++) ob.h[i] = (half_t)(e[i] * inv);
  *reinterpret_cast<H8*>(P + (size_t)blockIdx.x * NB + t * 8) = ob;
}

// ---------------- launcher
extern "C" void kernel_launch(void* const* d_in, const int* in_sizes, int n_in,
                              void* d_out, int out_size, void* d_ws, size_t ws_size,
                              hipStream_t stream) {
  const float* x  = (const float*)d_in[0];
  const float* wq = (const float*)d_in[1];
  const float* bq = (const float*)d_in[2];
  const float* wk = (const float*)d_in[3];
  const float* wv = (const float*)d_in[5];
  const float* bv = (const float*)d_in[6];
  float* out = (float*)d_out;

  const size_t MB = 1u << 20;
  if (ws_size < 196 * MB) return;

  char* ws = (char*)d_ws;
  half_t* xh   = (half_t*)(ws + 0);            // [B][N][C]    16 MB
  half_t* YTh  = (half_t*)(ws + 16 * MB);      // [B][N][C]    16 MB
  half_t* v    = (half_t*)(ws + 32 * MB);      // [B][C][N]    16 MB
  short*  Ss   = (short*)(ws + 48 * MB);       // [8][N][N]    64 MB (int16 logits, scale 256)
  float*  Gp   = (float*)(ws + 48 * MB);       // [8][C][C]     8 MB (overlay; dead before S)
  half_t* Pd   = (half_t*)(ws + 112 * MB);     // [8][N][N]    64 MB (dense P)
  half_t* xn   = (half_t*)(ws + 176 * MB);     // [B][C][N]    16 MB (fp16 residual copy)
  half_t* Gh   = (half_t*)(ws + 192 * MB);     // [C][C]      0.5 MB
  half_t* wvh  = (half_t*)(ws + 192 * MB + 512 * 1024);  // [C][C]  0.5 MB
  float*  u    = (float*)(ws + 193 * MB);                // [C]       2 KB
  float*  ub   = (float*)(ws + 193 * MB + 256 * 1024);   // [B][N]   64 KB

  prep_all<<<9730, 256, 0, stream>>>(x, wq, wk, wv, bq, xh, xn, wvh, u, Gp);
  prep2<<<5120, 256, 0, stream>>>(Gp, Gh, xh, u, ub);

  gemm_vyt<<<dim3(16, 4, 16), 256, 0, stream>>>(xh, wvh, Gh, bv, v, YTh);

  gemm_s256<<<dim3(8, 8, 8), 512, 0, stream>>>(xh, YTh, Ss, ub);

  softmax_rows<<<BB * NB, 256, 0, stream>>>(Ss, Pd);

  // PV on the s256 schedule
  gemm_pv256<<<dim3(8, 4, 8), 512, 0, stream>>>(v, Pd, xn, out);
}